// Round 3
// baseline (436.895 us; speedup 1.0000x reference)
//
#include <hip/hip_runtime.h>

#define T_STEPS 256
#define F_IN    16
#define LPB     16                      // lanes per batch element
#define BLOCK   256
#define B_PER_BLOCK (BLOCK / LPB)       // 16

__device__ __forceinline__ float fast_sig(float x) {
    float e = __builtin_amdgcn_exp2f(-1.44269504088896f * x);
    e = fminf(e, 1.0e30f);              // guard inf -> NaN in Newton
    float d = 1.0f + e;
    float r = __builtin_amdgcn_rcpf(d);
    return r * (2.0f - d * r);          // 1 Newton step
}

__device__ __forceinline__ float fast_tanh(float x) {
    float e = __builtin_amdgcn_exp2f(-2.88539008177793f * x);
    e = fminf(e, 1.0e30f);
    float d = 1.0f + e;
    float r = __builtin_amdgcn_rcpf(d);
    r = r * (2.0f - d * r);
    return 2.0f * r - 1.0f;
}

// sigmoid(sc*z)*sc + off : (sc,off)=(2,-1) -> tanh(z); (1,0) -> sigmoid(z)
__device__ __forceinline__ float sig_or_tanh(float z, float sc, float off) {
    float e = __builtin_amdgcn_exp2f(-1.44269504088896f * sc * z);
    e = fminf(e, 1.0e30f);
    float d = 1.0f + e;
    float r = __builtin_amdgcn_rcpf(d);
    r = r * (2.0f - d * r);
    return fmaf(r, sc, off);
}

__global__ __launch_bounds__(BLOCK, 2)
void lstm16_kernel(const float* __restrict__ past,   // [B,T,F]
                   const float* __restrict__ fut,    // [B,8]
                   const float* __restrict__ W1,     // [16,32]
                   const float* __restrict__ U1,     // [8,32]
                   const float* __restrict__ b1,     // [32]
                   const float* __restrict__ W2,     // [8,32]
                   const float* __restrict__ U2,     // [8,32]
                   const float* __restrict__ b2,     // [32]
                   const float* __restrict__ Wd1,    // [16,8]
                   const float* __restrict__ bd1,    // [8]
                   const float* __restrict__ Wd2,    // [8,8]
                   const float* __restrict__ bd2,    // [8]
                   const float* __restrict__ Wo,     // [8,4]
                   const float* __restrict__ bo,     // [4]
                   float* __restrict__ out)          // [B,4]
{
    const int tid = threadIdx.x;
    const int l   = tid & (LPB - 1);       // 0..15 within batch group
    const int j   = l & 7;                 // owned hidden index
    const int r   = l >> 3;                // role: 0 -> (i,g), 1 -> (f,o)
    const int b   = blockIdx.x * B_PER_BLOCK + (tid >> 4);

    // lane owns gate columns colA = l and colB = 16 + l  (of the 4H=32 cols)
    const int colA = l, colB = 16 + l;

    float wA[16], wB[16], uA[8], uB[8];
    float w2A[8], w2B[8], u2A[8], u2B[8];
    const float bA  = b1[colA], bB  = b1[colB];
    const float b2A = b2[colA], b2B = b2[colB];
#pragma unroll
    for (int f = 0; f < 16; ++f) { wA[f] = W1[f * 32 + colA]; wB[f] = W1[f * 32 + colB]; }
#pragma unroll
    for (int k = 0; k < 8; ++k) {
        uA[k]  = U1[k * 32 + colA];  uB[k]  = U1[k * 32 + colB];
        w2A[k] = W2[k * 32 + colA];  w2B[k] = W2[k * 32 + colB];
        u2A[k] = U2[k * 32 + colA];  u2B[k] = U2[k * 32 + colB];
    }

    const float sc  = r ? 1.0f :  2.0f;    // zB nonlinearity: r0 tanh, r1 sigmoid
    const float off = r ? 0.0f : -1.0f;

    const float* xrow = past + (size_t)b * (T_STEPS * F_IN);

    float c1 = 0.f, c2 = 0.f;
    float h1all[8], h2all[8];
#pragma unroll
    for (int k = 0; k < 8; ++k) { h1all[k] = 0.f; h2all[k] = 0.f; }

    // prefetch x(t=0) — 16 lanes of a group read the same 64B line (broadcast)
    float4 xn0 = *(const float4*)(xrow + 0);
    float4 xn1 = *(const float4*)(xrow + 4);
    float4 xn2 = *(const float4*)(xrow + 8);
    float4 xn3 = *(const float4*)(xrow + 12);

    for (int t = 0; t < T_STEPS; ++t) {
        float x[16];
        x[0]=xn0.x;  x[1]=xn0.y;  x[2]=xn0.z;  x[3]=xn0.w;
        x[4]=xn1.x;  x[5]=xn1.y;  x[6]=xn1.z;  x[7]=xn1.w;
        x[8]=xn2.x;  x[9]=xn2.y;  x[10]=xn2.z; x[11]=xn2.w;
        x[12]=xn3.x; x[13]=xn3.y; x[14]=xn3.z; x[15]=xn3.w;

        const int tn = (t + 1 < T_STEPS) ? (t + 1) : t;
        const float* xr = xrow + tn * F_IN;
        xn0 = *(const float4*)(xr + 0);
        xn1 = *(const float4*)(xr + 4);
        xn2 = *(const float4*)(xr + 8);
        xn3 = *(const float4*)(xr + 12);

        // ---- layer 1: z = x@W1 + b1 + h1@U1 (2 columns per lane) ----
        float zA = bA, zB = bB;
#pragma unroll
        for (int f = 0; f < 16; ++f) { zA = fmaf(x[f], wA[f], zA); zB = fmaf(x[f], wB[f], zB); }
#pragma unroll
        for (int k = 0; k < 8; ++k)  { zA = fmaf(h1all[k], uA[k], zA); zB = fmaf(h1all[k], uB[k], zB); }

        float sA = fast_sig(zA);                 // r0: sig(i)   r1: sig(f)
        float vB = sig_or_tanh(zB, sc, off);     // r0: tanh(g)  r1: sig(o)
        float p  = sA * vB;                      // r0: sig(i)*tanh(g)

        float e1 = __shfl_xor(r ? sA : p, 8);    // r0 gets f̂ ; r1 gets p
        float e2 = __shfl_xor(vB, 8);            // r0 gets ô ; r1 junk

        float fhat = r ? sA : e1;
        float pp   = r ? e1 : p;
        float ohat = r ? vB : e2;
        c1 = fmaf(fhat, c1, pp);
        float h1 = ohat * fast_tanh(c1);

        float h1n[8];
#pragma unroll
        for (int k = 0; k < 8; ++k) h1n[k] = __shfl(h1, k, LPB);

        // ---- layer 2: z = h1@W2 + b2 + h2@U2 ----
        // U2 dot first (independent of the h1 gather -> hides bpermute latency)
        float zA2 = b2A, zB2 = b2B;
#pragma unroll
        for (int k = 0; k < 8; ++k) { zA2 = fmaf(h2all[k], u2A[k], zA2); zB2 = fmaf(h2all[k], u2B[k], zB2); }
#pragma unroll
        for (int k = 0; k < 8; ++k) {
            h1all[k] = h1n[k];
            zA2 = fmaf(h1n[k], w2A[k], zA2);
            zB2 = fmaf(h1n[k], w2B[k], zB2);
        }

        float sA2 = fast_sig(zA2);
        float vB2 = sig_or_tanh(zB2, sc, off);
        float p2  = sA2 * vB2;

        float f1 = __shfl_xor(r ? sA2 : p2, 8);
        float f2 = __shfl_xor(vB2, 8);

        float fhat2 = r ? sA2 : f1;
        float pp2   = r ? f1  : p2;
        float ohat2 = r ? vB2 : f2;
        c2 = fmaf(fhat2, c2, pp2);
        float h2 = ohat2 * fast_tanh(c2);

#pragma unroll
        for (int k = 0; k < 8; ++k) h2all[k] = __shfl(h2, k, LPB);
    }

    // ---- head: concat(h2, fut) -> relu8 -> relu8 -> 4  (both halves redundant) ----
    float fm[8];
#pragma unroll
    for (int k = 0; k < 8; ++k) fm[k] = fut[b * 8 + k];

    float s1 = bd1[j];
#pragma unroll
    for (int k = 0; k < 8; ++k) s1 = fmaf(h2all[k], Wd1[k * 8 + j], s1);
#pragma unroll
    for (int k = 0; k < 8; ++k) s1 = fmaf(fm[k], Wd1[(8 + k) * 8 + j], s1);
    s1 = fmaxf(s1, 0.f);

    float d1all[8];
#pragma unroll
    for (int k = 0; k < 8; ++k) d1all[k] = __shfl(s1, k, LPB);

    float s2 = bd2[j];
#pragma unroll
    for (int k = 0; k < 8; ++k) s2 = fmaf(d1all[k], Wd2[k * 8 + j], s2);
    s2 = fmaxf(s2, 0.f);

    float d2all[8];
#pragma unroll
    for (int k = 0; k < 8; ++k) d2all[k] = __shfl(s2, k, LPB);

    if (l < 4) {
        float so = bo[l];
#pragma unroll
        for (int k = 0; k < 8; ++k) so = fmaf(d2all[k], Wo[k * 4 + l], so);
        out[b * 4 + l] = so;
    }
}

extern "C" void kernel_launch(void* const* d_in, const int* in_sizes, int n_in,
                              void* d_out, int out_size, void* d_ws, size_t ws_size,
                              hipStream_t stream) {
    const float* past = (const float*)d_in[1];
    const float* fut  = (const float*)d_in[2];
    const float* W1   = (const float*)d_in[3];
    const float* U1   = (const float*)d_in[4];
    const float* b1   = (const float*)d_in[5];
    const float* W2   = (const float*)d_in[6];
    const float* U2   = (const float*)d_in[7];
    const float* b2   = (const float*)d_in[8];
    const float* Wd1  = (const float*)d_in[9];
    const float* bd1  = (const float*)d_in[10];
    const float* Wd2  = (const float*)d_in[11];
    const float* bd2  = (const float*)d_in[12];
    const float* Wo   = (const float*)d_in[13];
    const float* bo   = (const float*)d_in[14];
    float* out = (float*)d_out;

    const int B = in_sizes[2] / 8;                 // future_metadata is [B,8]
    const int grid = (B * LPB) / BLOCK;            // 8192*16/256 = 512 blocks

    lstm16_kernel<<<grid, BLOCK, 0, stream>>>(
        past, fut, W1, U1, b1, W2, U2, b2,
        Wd1, bd1, Wd2, bd2, Wo, bo, out);
}

// Round 4
// 399.233 us; speedup vs baseline: 1.0943x; 1.0943x over previous
//
#include <hip/hip_runtime.h>

#define T_STEPS 256
#define F_IN    16
#define LPB     16                      // lanes per batch element
#define BLOCK   256
#define B_PER_BLOCK (BLOCK / LPB)       // 16

// Force a value to live in a VGPR and be opaque to the compiler:
// the load feeding it cannot be sunk into the loop or rematerialized.
#define PIN(v) asm volatile("" : "+v"(v))

// ds_swizzle BitMode: new_lane = ((lane & and) | or) ^ xor, offset = (xor<<10)|(or<<5)|and
template<int IMM>
__device__ __forceinline__ float swz(float x) {
    return __int_as_float(__builtin_amdgcn_ds_swizzle(__float_as_int(x), IMM));
}
#define XOR8 0x201F                     // lane ^ 8  (and=0x1F, xor=8)

__device__ __forceinline__ float fast_sig(float x) {
    float e = __builtin_amdgcn_exp2f(-1.44269504088896f * x);
    e = fminf(e, 1.0e30f);              // guard inf -> NaN in Newton
    float d = 1.0f + e;
    float r = __builtin_amdgcn_rcpf(d);
    return r * (2.0f - d * r);          // 1 Newton step
}

__device__ __forceinline__ float fast_tanh(float x) {
    float e = __builtin_amdgcn_exp2f(-2.88539008177793f * x);
    e = fminf(e, 1.0e30f);
    float d = 1.0f + e;
    float r = __builtin_amdgcn_rcpf(d);
    r = r * (2.0f - d * r);
    return 2.0f * r - 1.0f;
}

// sigmoid(sc*z)*sc + off : (sc,off)=(2,-1) -> tanh(z); (1,0) -> sigmoid(z)
__device__ __forceinline__ float sig_or_tanh(float z, float sc, float off) {
    float e = __builtin_amdgcn_exp2f(-1.44269504088896f * sc * z);
    e = fminf(e, 1.0e30f);
    float d = 1.0f + e;
    float r = __builtin_amdgcn_rcpf(d);
    r = r * (2.0f - d * r);
    return fmaf(r, sc, off);
}

__global__ __launch_bounds__(BLOCK, 2)
void lstm16_kernel(const float* __restrict__ past,   // [B,T,F]
                   const float* __restrict__ fut,    // [B,8]
                   const float* __restrict__ W1,     // [16,32]
                   const float* __restrict__ U1,     // [8,32]
                   const float* __restrict__ b1,     // [32]
                   const float* __restrict__ W2,     // [8,32]
                   const float* __restrict__ U2,     // [8,32]
                   const float* __restrict__ b2,     // [32]
                   const float* __restrict__ Wd1,    // [16,8]
                   const float* __restrict__ bd1,    // [8]
                   const float* __restrict__ Wd2,    // [8,8]
                   const float* __restrict__ bd2,    // [8]
                   const float* __restrict__ Wo,     // [8,4]
                   const float* __restrict__ bo,     // [4]
                   float* __restrict__ out)          // [B,4]
{
    const int tid = threadIdx.x;
    const int l   = tid & (LPB - 1);       // 0..15 within batch group
    const int j   = l & 7;                 // owned hidden index
    const int r   = l >> 3;                // role: 0 -> (i,g), 1 -> (f,o)
    const int b   = blockIdx.x * B_PER_BLOCK + (tid >> 4);

    // lane owns gate columns colA = l and colB = 16 + l  (of the 4H=32 cols)
    const int colA = l, colB = 16 + l;

    float wA[16], wB[16], uA[8], uB[8];
    float w2A[8], w2B[8], u2A[8], u2B[8];
    float bA  = b1[colA], bB  = b1[colB];
    float b2A = b2[colA], b2B = b2[colB];
#pragma unroll
    for (int f = 0; f < 16; ++f) { wA[f] = W1[f * 32 + colA]; wB[f] = W1[f * 32 + colB]; }
#pragma unroll
    for (int k = 0; k < 8; ++k) {
        uA[k]  = U1[k * 32 + colA];  uB[k]  = U1[k * 32 + colB];
        w2A[k] = W2[k * 32 + colA];  w2B[k] = W2[k * 32 + colB];
        u2A[k] = U2[k * 32 + colA];  u2B[k] = U2[k * 32 + colB];
    }

    // ---- pin all weights into VGPRs: loads cannot sink into the t-loop ----
    PIN(bA); PIN(bB); PIN(b2A); PIN(b2B);
#pragma unroll
    for (int f = 0; f < 16; ++f) { PIN(wA[f]); PIN(wB[f]); }
#pragma unroll
    for (int k = 0; k < 8; ++k) {
        PIN(uA[k]); PIN(uB[k]); PIN(w2A[k]); PIN(w2B[k]); PIN(u2A[k]); PIN(u2B[k]);
    }

    const float sc  = r ? 1.0f :  2.0f;    // zB nonlinearity: r0 tanh, r1 sigmoid
    const float off = r ? 0.0f : -1.0f;

    const float* xrow = past + (size_t)b * (T_STEPS * F_IN);

    float c1 = 0.f, c2 = 0.f;
    float h1all[8], h2all[8];
#pragma unroll
    for (int k = 0; k < 8; ++k) { h1all[k] = 0.f; h2all[k] = 0.f; }

    // prefetch x(t=0) — 16 lanes of a group read the same 64B line (broadcast)
    float4 xn0 = *(const float4*)(xrow + 0);
    float4 xn1 = *(const float4*)(xrow + 4);
    float4 xn2 = *(const float4*)(xrow + 8);
    float4 xn3 = *(const float4*)(xrow + 12);

    for (int t = 0; t < T_STEPS; ++t) {
        float x[16];
        x[0]=xn0.x;  x[1]=xn0.y;  x[2]=xn0.z;  x[3]=xn0.w;
        x[4]=xn1.x;  x[5]=xn1.y;  x[6]=xn1.z;  x[7]=xn1.w;
        x[8]=xn2.x;  x[9]=xn2.y;  x[10]=xn2.z; x[11]=xn2.w;
        x[12]=xn3.x; x[13]=xn3.y; x[14]=xn3.z; x[15]=xn3.w;

        const int tn = (t + 1 < T_STEPS) ? (t + 1) : t;
        const float* xr = xrow + tn * F_IN;
        xn0 = *(const float4*)(xr + 0);
        xn1 = *(const float4*)(xr + 4);
        xn2 = *(const float4*)(xr + 8);
        xn3 = *(const float4*)(xr + 12);

        // ---- layer 1: z = x@W1 + b1 + h1@U1 (2 cols/lane, 2 partial chains) ----
        float zA0 = bA, zB0 = bB, zA1 = 0.f, zB1 = 0.f;
#pragma unroll
        for (int f = 0; f < 8; ++f)  { zA0 = fmaf(x[f], wA[f], zA0); zB0 = fmaf(x[f], wB[f], zB0); }
#pragma unroll
        for (int f = 8; f < 16; ++f) { zA1 = fmaf(x[f], wA[f], zA1); zB1 = fmaf(x[f], wB[f], zB1); }
#pragma unroll
        for (int k = 0; k < 4; ++k)  { zA0 = fmaf(h1all[k], uA[k], zA0); zB0 = fmaf(h1all[k], uB[k], zB0); }
#pragma unroll
        for (int k = 4; k < 8; ++k)  { zA1 = fmaf(h1all[k], uA[k], zA1); zB1 = fmaf(h1all[k], uB[k], zB1); }
        const float zA = zA0 + zA1, zB = zB0 + zB1;

        float sA = fast_sig(zA);                 // r0: sig(i)   r1: sig(f)
        float vB = sig_or_tanh(zB, sc, off);     // r0: tanh(g)  r1: sig(o)
        float p  = sA * vB;                      // r0: sig(i)*tanh(g)

        float e1 = swz<XOR8>(r ? sA : p);        // r0 gets f̂ ; r1 gets p
        float e2 = swz<XOR8>(vB);                // r0 gets ô ; r1 junk

        float fhat = r ? sA : e1;
        float pp   = r ? e1 : p;
        float ohat = r ? vB : e2;
        c1 = fmaf(fhat, c1, pp);
        float h1 = ohat * fast_tanh(c1);

        // broadcast lane k of each 16-group: offset = (k<<5) | 0x10
        float h1n[8];
        h1n[0]=swz<0x010>(h1); h1n[1]=swz<0x030>(h1);
        h1n[2]=swz<0x050>(h1); h1n[3]=swz<0x070>(h1);
        h1n[4]=swz<0x090>(h1); h1n[5]=swz<0x0B0>(h1);
        h1n[6]=swz<0x0D0>(h1); h1n[7]=swz<0x0F0>(h1);

        // ---- layer 2: z = h1@W2 + b2 + h2@U2 (U2 dot first: independent of gather) ----
        float zA2a = b2A, zB2a = b2B, zA2b = 0.f, zB2b = 0.f;
#pragma unroll
        for (int k = 0; k < 8; ++k) { zA2a = fmaf(h2all[k], u2A[k], zA2a); zB2a = fmaf(h2all[k], u2B[k], zB2a); }
#pragma unroll
        for (int k = 0; k < 8; ++k) {
            h1all[k] = h1n[k];
            zA2b = fmaf(h1n[k], w2A[k], zA2b);
            zB2b = fmaf(h1n[k], w2B[k], zB2b);
        }
        const float zA2 = zA2a + zA2b, zB2 = zB2a + zB2b;

        float sA2 = fast_sig(zA2);
        float vB2 = sig_or_tanh(zB2, sc, off);
        float p2  = sA2 * vB2;

        float f1 = swz<XOR8>(r ? sA2 : p2);
        float f2 = swz<XOR8>(vB2);

        float fhat2 = r ? sA2 : f1;
        float pp2   = r ? f1  : p2;
        float ohat2 = r ? vB2 : f2;
        c2 = fmaf(fhat2, c2, pp2);
        float h2 = ohat2 * fast_tanh(c2);

        h2all[0]=swz<0x010>(h2); h2all[1]=swz<0x030>(h2);
        h2all[2]=swz<0x050>(h2); h2all[3]=swz<0x070>(h2);
        h2all[4]=swz<0x090>(h2); h2all[5]=swz<0x0B0>(h2);
        h2all[6]=swz<0x0D0>(h2); h2all[7]=swz<0x0F0>(h2);
    }

    // ---- head: concat(h2, fut) -> relu8 -> relu8 -> 4  (both halves redundant) ----
    float fm[8];
#pragma unroll
    for (int k = 0; k < 8; ++k) fm[k] = fut[b * 8 + k];

    float s1 = bd1[j];
#pragma unroll
    for (int k = 0; k < 8; ++k) s1 = fmaf(h2all[k], Wd1[k * 8 + j], s1);
#pragma unroll
    for (int k = 0; k < 8; ++k) s1 = fmaf(fm[k], Wd1[(8 + k) * 8 + j], s1);
    s1 = fmaxf(s1, 0.f);

    float d1all[8];
#pragma unroll
    for (int k = 0; k < 8; ++k) d1all[k] = __shfl(s1, k, LPB);

    float s2 = bd2[j];
#pragma unroll
    for (int k = 0; k < 8; ++k) s2 = fmaf(d1all[k], Wd2[k * 8 + j], s2);
    s2 = fmaxf(s2, 0.f);

    float d2all[8];
#pragma unroll
    for (int k = 0; k < 8; ++k) d2all[k] = __shfl(s2, k, LPB);

    if (l < 4) {
        float so = bo[l];
#pragma unroll
        for (int k = 0; k < 8; ++k) so = fmaf(d2all[k], Wo[k * 4 + l], so);
        out[b * 4 + l] = so;
    }
}

extern "C" void kernel_launch(void* const* d_in, const int* in_sizes, int n_in,
                              void* d_out, int out_size, void* d_ws, size_t ws_size,
                              hipStream_t stream) {
    const float* past = (const float*)d_in[1];
    const float* fut  = (const float*)d_in[2];
    const float* W1   = (const float*)d_in[3];
    const float* U1   = (const float*)d_in[4];
    const float* b1   = (const float*)d_in[5];
    const float* W2   = (const float*)d_in[6];
    const float* U2   = (const float*)d_in[7];
    const float* b2   = (const float*)d_in[8];
    const float* Wd1  = (const float*)d_in[9];
    const float* bd1  = (const float*)d_in[10];
    const float* Wd2  = (const float*)d_in[11];
    const float* bd2  = (const float*)d_in[12];
    const float* Wo   = (const float*)d_in[13];
    const float* bo   = (const float*)d_in[14];
    float* out = (float*)d_out;

    const int B = in_sizes[2] / 8;                 // future_metadata is [B,8]
    const int grid = (B * LPB) / BLOCK;            // 8192*16/256 = 512 blocks

    lstm16_kernel<<<grid, BLOCK, 0, stream>>>(
        past, fut, W1, U1, b1, W2, U2, b2,
        Wd1, bd1, Wd2, bd2, Wo, bo, out);
}

// Round 6
// 337.704 us; speedup vs baseline: 1.2937x; 1.1822x over previous
//
#include <hip/hip_runtime.h>

#define T_STEPS 256
#define LPB     16                      // lanes per batch element
#define BLOCK   256
#define B_PER_BLOCK (BLOCK / LPB)       // 16

// Keep a value opaque/live in a VGPR (loads can't sink into the loop).
#define PIN(v) asm volatile("" : "+v"(v))

// DPP controls (gfx9 lineage): row = 16 lanes.
// Semantics: row_ror:N  => dst[n] = src[(n - N) & 15]   (data moves to HIGHER lanes)
#define ROR1 0x121
#define ROR8 0x128                      // (n-8)&15 == n^8 : direction-invariant

template<int CTRL>
__device__ __forceinline__ float dppf(float x) {
    return __int_as_float(__builtin_amdgcn_update_dpp(
        0, __float_as_int(x), CTRL, 0xF, 0xF, true));
}

// sigmoid via exp2+rcp (v_rcp ~1ulp; rcp(inf)=0 is the correct saturation)
__device__ __forceinline__ float fsig(float x) {
    return __builtin_amdgcn_rcpf(1.0f + __builtin_amdgcn_exp2f(-1.44269504088896f * x));
}
__device__ __forceinline__ float ftanh(float x) {
    return fmaf(__builtin_amdgcn_rcpf(1.0f + __builtin_amdgcn_exp2f(-2.88539008177793f * x)),
                2.0f, -1.0f);
}
// (sc,off)=(2,-1) -> tanh(z); (1,0) -> sigmoid(z)
__device__ __forceinline__ float fsig_or_tanh(float z, float sc, float off) {
    float r = __builtin_amdgcn_rcpf(1.0f + __builtin_amdgcn_exp2f(-1.44269504088896f * sc * z));
    return fmaf(r, sc, off);
}

__attribute__((amdgpu_waves_per_eu(2, 2)))
__global__ __launch_bounds__(BLOCK)
void lstm_dpp_kernel(const float* __restrict__ past,   // [B,T,16]
                     const float* __restrict__ fut,    // [B,8]
                     const float* __restrict__ W1,     // [16,32]
                     const float* __restrict__ U1,     // [8,32]
                     const float* __restrict__ b1,     // [32]
                     const float* __restrict__ W2,     // [8,32]
                     const float* __restrict__ U2,     // [8,32]
                     const float* __restrict__ b2,     // [32]
                     const float* __restrict__ Wd1,    // [16,8]
                     const float* __restrict__ bd1,    // [8]
                     const float* __restrict__ Wd2,    // [8,8]
                     const float* __restrict__ bd2,    // [8]
                     const float* __restrict__ Wo,     // [8,4]
                     const float* __restrict__ bo,     // [4]
                     float* __restrict__ out)          // [B,4]
{
    const int tid = threadIdx.x;
    const int l   = tid & (LPB - 1);     // 0..15 within batch group
    const int j   = l & 7;               // owned hidden index
    const int r   = l >> 3;              // role: 0 -> (i,g), 1 -> (f,o)
    const int b   = blockIdx.x * B_PER_BLOCK + (tid >> 4);
    const int colA = l, colB = 16 + l;   // gate cols: 0-7 i, 8-15 f, 16-23 g, 24-31 o

    // ---- per-lane weights; recurrent ones in ROTATED order for the DPP dot ----
    // After rr applications of ROR1, lane l holds h_{(j - rr) & 7}.
    float wA[16], wB[16];
#pragma unroll
    for (int f = 0; f < 16; ++f) { wA[f] = W1[f * 32 + colA]; wB[f] = W1[f * 32 + colB]; }
    float uAr[8], uBr[8], w2Ar[8], w2Br[8], u2Ar[8], u2Br[8];
#pragma unroll
    for (int rr = 0; rr < 8; ++rr) {
        const int k = (j - rr) & 7;      // matches ROR1^rr
        uAr[rr]  = U1[k * 32 + colA];  uBr[rr]  = U1[k * 32 + colB];
        w2Ar[rr] = W2[k * 32 + colA];  w2Br[rr] = W2[k * 32 + colB];
        u2Ar[rr] = U2[k * 32 + colA];  u2Br[rr] = U2[k * 32 + colB];
    }
    float bA = b1[colA], bB = b1[colB], b2A = b2[colA], b2B = b2[colB];

    PIN(bA); PIN(bB); PIN(b2A); PIN(b2B);
#pragma unroll
    for (int f = 0; f < 16; ++f) { PIN(wA[f]); PIN(wB[f]); }
#pragma unroll
    for (int rr = 0; rr < 8; ++rr) {
        PIN(uAr[rr]); PIN(uBr[rr]); PIN(w2Ar[rr]); PIN(w2Br[rr]); PIN(u2Ar[rr]); PIN(u2Br[rr]);
    }

    const float sc  = r ? 1.0f :  2.0f;
    const float off = r ? 0.0f : -1.0f;
    const float* xrow = past + (size_t)b * (T_STEPS * 16);

    float c1 = 0.f, c2 = 0.f, h1d = 0.f, h2d = 0.f;   // h replicated in both roles

#define XT(xv, idx) zA##_c0 = fmaf(xv, wA[idx], zA##_c0); zB##_c0 = fmaf(xv, wB[idx], zB##_c0)
#define XU(xv, idx) zA##_c1 = fmaf(xv, wA[idx], zA##_c1); zB##_c1 = fmaf(xv, wB[idx], zB##_c1)

    auto step = [&](float4 q0, float4 q1, float4 q2, float4 q3) {
        // ---- layer 1: z = x@W1 + b1 + h1@U1 ----
        float zA_c0 = bA, zB_c0 = bB, zA_c1 = 0.f, zB_c1 = 0.f;
        XT(q0.x, 0);  XU(q0.y, 1);  XT(q0.z, 2);  XU(q0.w, 3);
        XT(q1.x, 4);  XU(q1.y, 5);  XT(q1.z, 6);  XU(q1.w, 7);
        XT(q2.x, 8);  XU(q2.y, 9);  XT(q2.z, 10); XU(q2.w, 11);
        XT(q3.x, 12); XU(q3.y, 13); XT(q3.z, 14); XU(q3.w, 15);
        // rotate-and-accumulate h1 dot (no LDS)
        float hr = h1d;
        zA_c0 = fmaf(hr, uAr[0], zA_c0); zB_c0 = fmaf(hr, uBr[0], zB_c0);
#pragma unroll
        for (int rr = 1; rr < 8; ++rr) {
            hr = dppf<ROR1>(hr);
            if (rr & 1) { zA_c1 = fmaf(hr, uAr[rr], zA_c1); zB_c1 = fmaf(hr, uBr[rr], zB_c1); }
            else        { zA_c0 = fmaf(hr, uAr[rr], zA_c0); zB_c0 = fmaf(hr, uBr[rr], zB_c0); }
        }
        const float zA = zA_c0 + zA_c1, zB = zB_c0 + zB_c1;

        float sA = fsig(zA);                    // r0: sig(i)   r1: sig(f)
        float vB = fsig_or_tanh(zB, sc, off);   // r0: tanh(g)  r1: sig(o)
        float p  = sA * vB;
        float e1 = dppf<ROR8>(r ? sA : p);      // role exchange (lane^8)
        float e2 = dppf<ROR8>(vB);
        float fh = r ? sA : e1;
        float pp = r ? e1 : p;
        float oh = r ? vB : e2;
        c1  = fmaf(fh, c1, pp);
        h1d = oh * ftanh(c1);                   // identical in both roles

        // ---- layer 2: z = h1@W2 + b2 + h2@U2 (two rotation chains) ----
        float g1 = h1d, g2 = h2d;
        float yA_c0 = b2A, yB_c0 = b2B, yA_c1 = 0.f, yB_c1 = 0.f;
        yA_c0 = fmaf(g1, w2Ar[0], yA_c0); yB_c0 = fmaf(g1, w2Br[0], yB_c0);
        yA_c1 = fmaf(g2, u2Ar[0], yA_c1); yB_c1 = fmaf(g2, u2Br[0], yB_c1);
#pragma unroll
        for (int rr = 1; rr < 8; ++rr) {
            g1 = dppf<ROR1>(g1);
            g2 = dppf<ROR1>(g2);
            if (rr & 1) {
                yA_c1 = fmaf(g1, w2Ar[rr], yA_c1); yB_c1 = fmaf(g1, w2Br[rr], yB_c1);
                yA_c0 = fmaf(g2, u2Ar[rr], yA_c0); yB_c0 = fmaf(g2, u2Br[rr], yB_c0);
            } else {
                yA_c0 = fmaf(g1, w2Ar[rr], yA_c0); yB_c0 = fmaf(g1, w2Br[rr], yB_c0);
                yA_c1 = fmaf(g2, u2Ar[rr], yA_c1); yB_c1 = fmaf(g2, u2Br[rr], yB_c1);
            }
        }
        const float zA2 = yA_c0 + yA_c1, zB2 = yB_c0 + yB_c1;

        float sA2 = fsig(zA2);
        float vB2 = fsig_or_tanh(zB2, sc, off);
        float p2  = sA2 * vB2;
        float f1  = dppf<ROR8>(r ? sA2 : p2);
        float f2  = dppf<ROR8>(vB2);
        float fh2 = r ? sA2 : f1;
        float pp2 = r ? f1  : p2;
        float oh2 = r ? vB2 : f2;
        c2  = fmaf(fh2, c2, pp2);
        h2d = oh2 * ftanh(c2);
    };
#undef XT
#undef XU

    // double-buffered x: unroll by 2, reload a buffer right after consuming it
    float4 A0 = *(const float4*)(xrow + 0),  A1 = *(const float4*)(xrow + 4);
    float4 A2 = *(const float4*)(xrow + 8),  A3 = *(const float4*)(xrow + 12);
    float4 B0 = *(const float4*)(xrow + 16), B1 = *(const float4*)(xrow + 20);
    float4 B2 = *(const float4*)(xrow + 24), B3 = *(const float4*)(xrow + 28);

    for (int t = 0; t < T_STEPS; t += 2) {
        step(A0, A1, A2, A3);
        {
            const int ta = (t + 2 < T_STEPS) ? t + 2 : 0;   // dead load at tail
            const float* pa = xrow + ta * 16;
            A0 = *(const float4*)(pa + 0); A1 = *(const float4*)(pa + 4);
            A2 = *(const float4*)(pa + 8); A3 = *(const float4*)(pa + 12);
        }
        step(B0, B1, B2, B3);
        {
            const int tb = (t + 3 < T_STEPS) ? t + 3 : 0;
            const float* pb = xrow + tb * 16;
            B0 = *(const float4*)(pb + 0); B1 = *(const float4*)(pb + 4);
            B2 = *(const float4*)(pb + 8); B3 = *(const float4*)(pb + 12);
        }
    }

    // ---- head: concat(h2, fut) -> relu8 -> relu8 -> 4 (rotation dots, no LDS) ----
    float fm[8];
#pragma unroll
    for (int k = 0; k < 8; ++k) fm[k] = fut[b * 8 + k];

    float s1 = bd1[j];
    {
        float t2 = h2d;
        s1 = fmaf(t2, Wd1[j * 8 + j], s1);
#pragma unroll
        for (int rr = 1; rr < 8; ++rr) {
            t2 = dppf<ROR1>(t2);
            s1 = fmaf(t2, Wd1[((j - rr) & 7) * 8 + j], s1);
        }
    }
#pragma unroll
    for (int k = 0; k < 8; ++k) s1 = fmaf(fm[k], Wd1[(8 + k) * 8 + j], s1);
    s1 = fmaxf(s1, 0.f);

    float s2 = bd2[j];
    {
        float t3 = s1;
        s2 = fmaf(t3, Wd2[j * 8 + j], s2);
#pragma unroll
        for (int rr = 1; rr < 8; ++rr) {
            t3 = dppf<ROR1>(t3);
            s2 = fmaf(t3, Wd2[((j - rr) & 7) * 8 + j], s2);
        }
    }
    s2 = fmaxf(s2, 0.f);

    // gather all 8 s2 values via rotation (done by ALL lanes: DPP needs live sources)
    float d2a[8];
    {
        float t4 = s2;
        d2a[0] = t4;
#pragma unroll
        for (int rr = 1; rr < 8; ++rr) { t4 = dppf<ROR1>(t4); d2a[rr] = t4; }
    }
    if (l < 4) {
        float so = bo[l];
#pragma unroll
        for (int rr = 0; rr < 8; ++rr) so = fmaf(d2a[rr], Wo[((l - rr) & 7) * 4 + l], so);
        out[b * 4 + l] = so;
    }
}

extern "C" void kernel_launch(void* const* d_in, const int* in_sizes, int n_in,
                              void* d_out, int out_size, void* d_ws, size_t ws_size,
                              hipStream_t stream) {
    const float* past = (const float*)d_in[1];
    const float* fut  = (const float*)d_in[2];
    const float* W1   = (const float*)d_in[3];
    const float* U1   = (const float*)d_in[4];
    const float* b1   = (const float*)d_in[5];
    const float* W2   = (const float*)d_in[6];
    const float* U2   = (const float*)d_in[7];
    const float* b2   = (const float*)d_in[8];
    const float* Wd1  = (const float*)d_in[9];
    const float* bd1  = (const float*)d_in[10];
    const float* Wd2  = (const float*)d_in[11];
    const float* bd2  = (const float*)d_in[12];
    const float* Wo   = (const float*)d_in[13];
    const float* bo   = (const float*)d_in[14];
    float* out = (float*)d_out;

    const int B = in_sizes[2] / 8;                 // future_metadata is [B,8]
    const int grid = (B * LPB) / BLOCK;            // 512 blocks

    lstm_dpp_kernel<<<grid, BLOCK, 0, stream>>>(
        past, fut, W1, U1, b1, W2, U2, b2,
        Wd1, bd1, Wd2, bd2, Wo, bo, out);
}

// Round 7
// 289.607 us; speedup vs baseline: 1.5086x; 1.1661x over previous
//
#include <hip/hip_runtime.h>

#define T_STEPS 256
#define LPB     16                      // lanes per batch element
#define BLOCK   256
#define B_PER_BLOCK (BLOCK / LPB)       // 16
#define WAVES   (BLOCK / 64)            // 4
#define NSLOT   4                       // 4 slots x 4 steps = 16-step prefetch

typedef float v2f __attribute__((ext_vector_type(2)));

// Keep a value opaque/live (loads can't sink into the loop).
#define PIN2(v) asm volatile("" : "+v"(v))

// DPP: row_ror:N => dst[n] = src[(n - N) & 15]  (verified round 6)
#define ROR1 0x121
#define ROR8 0x128                      // (n-8)&15 == n^8

template<int CTRL>
__device__ __forceinline__ float dppf(float x) {
    return __int_as_float(__builtin_amdgcn_update_dpp(
        0, __float_as_int(x), CTRL, 0xF, 0xF, true));
}

__device__ __forceinline__ float fsig(float x) {
    return __builtin_amdgcn_rcpf(1.0f + __builtin_amdgcn_exp2f(-1.44269504088896f * x));
}
__device__ __forceinline__ float ftanh(float x) {
    return fmaf(__builtin_amdgcn_rcpf(1.0f + __builtin_amdgcn_exp2f(-2.88539008177793f * x)),
                2.0f, -1.0f);
}
__device__ __forceinline__ float fsig_or_tanh(float z, float sc, float off) {
    float r = __builtin_amdgcn_rcpf(1.0f + __builtin_amdgcn_exp2f(-1.44269504088896f * sc * z));
    return fmaf(r, sc, off);
}

__attribute__((amdgpu_waves_per_eu(2, 2)))
__global__ __launch_bounds__(BLOCK)
void lstm_pk_kernel(const float* __restrict__ past,   // [B,T,16]
                    const float* __restrict__ fut,    // [B,8]
                    const float* __restrict__ W1,     // [16,32]
                    const float* __restrict__ U1,     // [8,32]
                    const float* __restrict__ b1,     // [32]
                    const float* __restrict__ W2,     // [8,32]
                    const float* __restrict__ U2,     // [8,32]
                    const float* __restrict__ b2,     // [32]
                    const float* __restrict__ Wd1,    // [16,8]
                    const float* __restrict__ bd1,    // [8]
                    const float* __restrict__ Wd2,    // [8,8]
                    const float* __restrict__ bd2,    // [8]
                    const float* __restrict__ Wo,     // [8,4]
                    const float* __restrict__ bo,     // [4]
                    float* __restrict__ out)          // [B,4]
{
    const int tid = threadIdx.x;
    const int l   = tid & (LPB - 1);     // 0..15 within batch group
    const int j   = l & 7;               // owned hidden index
    const int r   = l >> 3;              // role: 0 -> (i,g), 1 -> (f,o)
    const int g   = tid >> 4;            // group in block (0..15)
    const int gw  = g & 3;               // group within wave (0..3)
    const int wid = tid >> 6;            // wave in block (0..3)
    const int b   = blockIdx.x * B_PER_BLOCK + g;
    const int colA = l, colB = 16 + l;   // gate cols: 0-7 i, 8-15 f, 16-23 g, 24-31 o

    // per-wave x ring: [slot][float] ; slot layout = [gw][t'][f] (= lane-linear 16B chunks)
    __shared__ float ring[WAVES][NSLOT][256];

    // ---- packed weights: pairs over the reduction index ----
    v2f wAp[8], wBp[8];                  // x-dot: pair f = {2c, 2c+1}
#pragma unroll
    for (int c = 0; c < 8; ++c) {
        wAp[c] = v2f{W1[(2*c)*32 + colA], W1[(2*c+1)*32 + colA]};
        wBp[c] = v2f{W1[(2*c)*32 + colB], W1[(2*c+1)*32 + colB]};
    }
    // rotation dots: pair rr = {2c, 2c+1}, weight row k(rr) = (j - rr) & 7 (dir verified r6)
    v2f uAp[4], uBp[4], w2Ap[4], w2Bp[4], u2Ap[4], u2Bp[4];
#pragma unroll
    for (int c = 0; c < 4; ++c) {
        const int k0 = (j - 2*c) & 7, k1 = (j - (2*c+1)) & 7;
        uAp[c]  = v2f{U1[k0*32 + colA], U1[k1*32 + colA]};
        uBp[c]  = v2f{U1[k0*32 + colB], U1[k1*32 + colB]};
        w2Ap[c] = v2f{W2[k0*32 + colA], W2[k1*32 + colA]};
        w2Bp[c] = v2f{W2[k0*32 + colB], W2[k1*32 + colB]};
        u2Ap[c] = v2f{U2[k0*32 + colA], U2[k1*32 + colA]};
        u2Bp[c] = v2f{U2[k0*32 + colB], U2[k1*32 + colB]};
    }
    float bA = b1[colA], bB = b1[colB], b2A = b2[colA], b2B = b2[colB];

#pragma unroll
    for (int c = 0; c < 8; ++c) { PIN2(wAp[c]); PIN2(wBp[c]); }
#pragma unroll
    for (int c = 0; c < 4; ++c) {
        PIN2(uAp[c]); PIN2(uBp[c]); PIN2(w2Ap[c]); PIN2(w2Bp[c]); PIN2(u2Ap[c]); PIN2(u2Bp[c]);
    }

    const float sc  = r ? 1.0f :  2.0f;
    const float off = r ? 0.0f : -1.0f;

    // producer: this lane fetches 16B of its OWN group's x: step t0+(l>>2), chunk (l&3)
    const float* srcbase = past + (size_t)b * (T_STEPS * 16) + (l >> 2) * 16 + (l & 3) * 4;

    // prologue: fill all 4 slots (t = 0,4,8,12)
#pragma unroll
    for (int s = 0; s < NSLOT; ++s)
        __builtin_amdgcn_global_load_lds(srcbase + s * 64, &ring[wid][s][0], 16, 0, 0);

    float c1 = 0.f, c2 = 0.f, h1d = 0.f, h2d = 0.f;
    v2f h1r2[4];                          // saved rotations of h1 (from L2's g1 chain)
#pragma unroll
    for (int c = 0; c < 4; ++c) h1r2[c] = v2f{0.f, 0.f};

    for (int t = 0; t < T_STEPS; t += 4) {
        const int slot = (t >> 2) & (NSLOT - 1);
        asm volatile("s_waitcnt vmcnt(3)" ::: "memory");   // oldest slot landed
        __builtin_amdgcn_sched_barrier(0);
        const v2f* sx = (const v2f*)&ring[wid][slot][gw * 64];

#pragma unroll
        for (int q = 0; q < 4; ++q) {
            const v2f* xp = sx + q * 8;   // 8 pairs = 16 floats for this step

            // ---- layer 1: z = x@W1 + b1 + h1@U1  (h1 rotations pre-saved) ----
            v2f aA = v2f{bA, 0.f}, aB = v2f{bB, 0.f};
#pragma unroll
            for (int c = 0; c < 8; ++c) {
                const v2f xv = xp[c];
                aA = xv * wAp[c] + aA;
                aB = xv * wBp[c] + aB;
            }
#pragma unroll
            for (int c = 0; c < 4; ++c) {
                aA = h1r2[c] * uAp[c] + aA;
                aB = h1r2[c] * uBp[c] + aB;
            }
            const float zA = aA.x + aA.y, zB = aB.x + aB.y;

            float sA = fsig(zA);                    // r0: sig(i)   r1: sig(f)
            float vB = fsig_or_tanh(zB, sc, off);   // r0: tanh(g)  r1: sig(o)
            float p  = sA * vB;
            float e1 = dppf<ROR8>(r ? sA : p);
            float e2 = dppf<ROR8>(vB);
            float fh = r ? sA : e1;
            float pp = r ? e1 : p;
            float oh = r ? vB : e2;
            c1  = fmaf(fh, c1, pp);
            h1d = oh * ftanh(c1);

            // ---- layer 2: dual rotation chains; g1 rotations saved for next L1 ----
            v2f dA = v2f{b2A, 0.f}, dB = v2f{b2B, 0.f};
            float g1v = h1d, g2v = h2d;
#pragma unroll
            for (int c = 0; c < 4; ++c) {
                v2f G1, G2;
                G1.x = g1v;  G2.x = g2v;
                g1v = dppf<ROR1>(g1v);  g2v = dppf<ROR1>(g2v);
                G1.y = g1v;  G2.y = g2v;
                if (c < 3) { g1v = dppf<ROR1>(g1v); g2v = dppf<ROR1>(g2v); }
                h1r2[c] = G1;
                dA = G1 * w2Ap[c] + dA;  dB = G1 * w2Bp[c] + dB;
                dA = G2 * u2Ap[c] + dA;  dB = G2 * u2Bp[c] + dB;
            }
            const float zA2 = dA.x + dA.y, zB2 = dB.x + dB.y;

            float sA2 = fsig(zA2);
            float vB2 = fsig_or_tanh(zB2, sc, off);
            float p2  = sA2 * vB2;
            float f1  = dppf<ROR8>(r ? sA2 : p2);
            float f2  = dppf<ROR8>(vB2);
            float fh2 = r ? sA2 : f1;
            float pp2 = r ? f1  : p2;
            float oh2 = r ? vB2 : f2;
            c2  = fmaf(fh2, c2, pp2);
            h2d = oh2 * ftanh(c2);
        }

        // refill this slot for t+16 (dead loads at tail clamp to t=0, never consumed)
        const int tnext = t + NSLOT * 4;
        const float* rs = (tnext < T_STEPS) ? (srcbase + tnext * 16) : srcbase;
        __builtin_amdgcn_global_load_lds(rs, &ring[wid][slot][0], 16, 0, 0);
    }
    // drain: in-flight LDS writes must not outlive the wave
    asm volatile("s_waitcnt vmcnt(0)" ::: "memory");

    // ---- head: concat(h2, fut) -> relu8 -> relu8 -> 4 (verified round 6) ----
    float fm[8];
#pragma unroll
    for (int k = 0; k < 8; ++k) fm[k] = fut[b * 8 + k];

    float s1 = bd1[j];
    {
        float t2 = h2d;
        s1 = fmaf(t2, Wd1[j * 8 + j], s1);
#pragma unroll
        for (int rr = 1; rr < 8; ++rr) {
            t2 = dppf<ROR1>(t2);
            s1 = fmaf(t2, Wd1[((j - rr) & 7) * 8 + j], s1);
        }
    }
#pragma unroll
    for (int k = 0; k < 8; ++k) s1 = fmaf(fm[k], Wd1[(8 + k) * 8 + j], s1);
    s1 = fmaxf(s1, 0.f);

    float s2 = bd2[j];
    {
        float t3 = s1;
        s2 = fmaf(t3, Wd2[j * 8 + j], s2);
#pragma unroll
        for (int rr = 1; rr < 8; ++rr) {
            t3 = dppf<ROR1>(t3);
            s2 = fmaf(t3, Wd2[((j - rr) & 7) * 8 + j], s2);
        }
    }
    s2 = fmaxf(s2, 0.f);

    float d2a[8];
    {
        float t4 = s2;
        d2a[0] = t4;
#pragma unroll
        for (int rr = 1; rr < 8; ++rr) { t4 = dppf<ROR1>(t4); d2a[rr] = t4; }
    }
    if (l < 4) {
        float so = bo[l];
#pragma unroll
        for (int rr = 0; rr < 8; ++rr) so = fmaf(d2a[rr], Wo[((l - rr) & 7) * 4 + l], so);
        out[b * 4 + l] = so;
    }
}

extern "C" void kernel_launch(void* const* d_in, const int* in_sizes, int n_in,
                              void* d_out, int out_size, void* d_ws, size_t ws_size,
                              hipStream_t stream) {
    const float* past = (const float*)d_in[1];
    const float* fut  = (const float*)d_in[2];
    const float* W1   = (const float*)d_in[3];
    const float* U1   = (const float*)d_in[4];
    const float* b1   = (const float*)d_in[5];
    const float* W2   = (const float*)d_in[6];
    const float* U2   = (const float*)d_in[7];
    const float* b2   = (const float*)d_in[8];
    const float* Wd1  = (const float*)d_in[9];
    const float* bd1  = (const float*)d_in[10];
    const float* Wd2  = (const float*)d_in[11];
    const float* bd2  = (const float*)d_in[12];
    const float* Wo   = (const float*)d_in[13];
    const float* bo   = (const float*)d_in[14];
    float* out = (float*)d_out;

    const int B = in_sizes[2] / 8;                 // future_metadata is [B,8]
    const int grid = (B * LPB) / BLOCK;            // 512 blocks

    lstm_pk_kernel<<<grid, BLOCK, 0, stream>>>(
        past, fut, W1, U1, b1, W2, U2, b2,
        Wd1, bd1, Wd2, bd2, Wo, bo, out);
}